// Round 5
// baseline (346.280 us; speedup 1.0000x reference)
//
#include <hip/hip_runtime.h>
#include <hip/hip_cooperative_groups.h>

namespace cg = cooperative_groups;

#define SS 4096
#define DM 1024
#define PSTRIDE 1056  // 16*66 f32 per block partial

typedef __attribute__((ext_vector_type(4))) float f32x4;
typedef __attribute__((ext_vector_type(8))) __bf16 bf16x8;
typedef __attribute__((ext_vector_type(8))) unsigned short ushort8;
typedef __attribute__((ext_vector_type(4))) unsigned short ushort4v;

#define NEGHUGE -3.0e38f
#define LOG2E 1.44269504f

__device__ __forceinline__ unsigned short f2b(float f) {
    unsigned u = __builtin_bit_cast(unsigned, f);
    u += 0x7fffu + ((u >> 16) & 1u);
    return (unsigned short)(u >> 16);
}

__device__ __forceinline__ f32x4 mfma16(ushort8 a, ushort8 b, f32x4 c) {
    return __builtin_amdgcn_mfma_f32_16x16x32_bf16(
        __builtin_bit_cast(bf16x8, a), __builtin_bit_cast(bf16x8, b), c, 0, 0, 0);
}

// ============================================================================
// Cooperative fused kernel, grid 512 x 256 (needs only 2 blocks/CU residency).
//  P1: W f32 -> bf16 (all 512 blocks, strided)
//  P2: QKV projection, N-split across waves, no LDS (blocks 0..255)
//  P3: attention split-KV partials: 256 groups x 2 chunks; 8 workers/group
//  P4: per-group combine of 2 chunk partials (blocks 0..255)
// ============================================================================
__global__ __launch_bounds__(256, 2) void fused_kernel(
    const float* __restrict__ x,
    const float* __restrict__ Wq, const float* __restrict__ bq,
    const float* __restrict__ Wk, const float* __restrict__ bk,
    const float* __restrict__ Wv, const float* __restrict__ bv,
    float* __restrict__ out,
    unsigned short* __restrict__ wb, unsigned short* __restrict__ Qs,
    unsigned short* __restrict__ Kb, unsigned short* __restrict__ VT,
    float* __restrict__ part)
{
    cg::grid_group grid = cg::this_grid();
    __shared__ unsigned short plds[4][16 * 64];  // 8KB, per-wave P (XOR-swizzled)
    __shared__ float scomb[4][16 * 66];          // 16.9KB

    const int bid = blockIdx.x;
    const int tid = threadIdx.x;
    const int w = tid >> 6, l = tid & 63;
    const int lc = l & 15;
    const int lg4 = l >> 4;
    const int lk = lg4 * 8;

    // ---------------- phase 1: convert W (3x [64][1024] f32) -> wb bf16 [192][1024]
    {
        int idx = bid * 256 + tid;          // 49152 f32x4 chunks total
        if (idx < 49152) {
            int i = idx * 4;
            const float* src;
            if (i < 65536) src = Wq + i;
            else if (i < 131072) src = Wk + (i - 65536);
            else src = Wv + (i - 131072);
            f32x4 v = *reinterpret_cast<const f32x4*>(src);
            ushort4v o;
            o[0] = f2b(v[0]); o[1] = f2b(v[1]); o[2] = f2b(v[2]); o[3] = f2b(v[3]);
            *reinterpret_cast<ushort4v*>(wb + i) = o;
        }
    }
    __threadfence();
    grid.sync();

    // ---------------- phase 2: projection. Block = 16 rows; wave w = cols [48w, 48w+48).
    if (bid < 256) {
        const int m0 = bid * 16;
        const int n0 = w * 48;
        f32x4 acc[3] = {};
        const float* xrow = x + (m0 + lc) * DM;
        const unsigned short* wrow = wb + (n0 + lc) * DM;
#pragma unroll 4
        for (int kk = 0; kk < DM; kk += 32) {
            const int k0 = kk + lk;
            f32x4 u = *reinterpret_cast<const f32x4*>(xrow + k0);
            f32x4 vv = *reinterpret_cast<const f32x4*>(xrow + k0 + 4);
            ushort8 a;
            a[0] = f2b(u[0]); a[1] = f2b(u[1]); a[2] = f2b(u[2]); a[3] = f2b(u[3]);
            a[4] = f2b(vv[0]); a[5] = f2b(vv[1]); a[6] = f2b(vv[2]); a[7] = f2b(vv[3]);
            acc[0] = mfma16(a, *reinterpret_cast<const ushort8*>(wrow + k0), acc[0]);
            acc[1] = mfma16(a, *reinterpret_cast<const ushort8*>(wrow + 16 * DM + k0), acc[1]);
            acc[2] = mfma16(a, *reinterpret_cast<const ushort8*>(wrow + 32 * DM + k0), acc[2]);
        }
#pragma unroll
        for (int nf = 0; nf < 3; nf++)
#pragma unroll
            for (int r = 0; r < 4; r++) {
                int col = n0 + nf * 16 + lc;
                int grow = m0 + lg4 * 4 + r;
                float s = acc[nf][r];
                if (col < 64) {
                    s += bq[col];
                    Qs[grow * 64 + col] = f2b(s * 0.125f);
                } else if (col < 128) {
                    s += bk[col - 64];
                    Kb[grow * 64 + col - 64] = f2b(s);
                } else {
                    s += bv[col - 128];
                    VT[(col - 128) * SS + grow] = f2b(s);
                }
            }
    }
    __threadfence();
    grid.sync();

    // ---------------- phase 3: attention split-KV partials (all 512 blocks).
    // bid -> (g = bid>>1, c = bid&1). Group g = Q rows [16g,16g+16).
    // Tile list [0,T) split across 8 workers (2 chunks x 4 waves), stride 8.
    {
        const int g = bid >> 1, c = bid & 1;
        const int q0 = g * 16;
        const int T = g / 4 + 1;
        const int W0 = c * 4 + w;

        ushort8 aq0 = *reinterpret_cast<const ushort8*>(Qs + (q0 + lc) * 64 + lk);
        ushort8 aq1 = *reinterpret_cast<const ushort8*>(Qs + (q0 + lc) * 64 + 32 + lk);

        float m4[4], l4[4];
        f32x4 o[4] = {};
#pragma unroll
        for (int r = 0; r < 4; r++) { m4[r] = NEGHUGE; l4[r] = 0.f; }

        char* myp = reinterpret_cast<char*>(plds[w]);

        for (int t = W0; t < T; t += 8) {
            const int kv0 = t * 64;
            f32x4 s[4] = {};
#pragma unroll
            for (int nf = 0; nf < 4; nf++) {
                const unsigned short* kr = Kb + (kv0 + nf * 16 + lc) * 64;
                ushort8 b0 = *reinterpret_cast<const ushort8*>(kr + lk);
                ushort8 b1 = *reinterpret_cast<const ushort8*>(kr + 32 + lk);
                s[nf] = mfma16(aq0, b0, s[nf]);
                s[nf] = mfma16(aq1, b1, s[nf]);
            }
            if (kv0 + 63 > q0) {
#pragma unroll
                for (int nf = 0; nf < 4; nf++)
#pragma unroll
                    for (int r = 0; r < 4; r++) {
                        int colg = kv0 + nf * 16 + lc;
                        int rowg = q0 + lg4 * 4 + r;
                        if (colg > rowg) s[nf][r] = NEGHUGE;
                    }
            }
#pragma unroll
            for (int r = 0; r < 4; r++) {
                float mx = fmaxf(fmaxf(s[0][r], s[1][r]), fmaxf(s[2][r], s[3][r]));
                mx = fmaxf(mx, __shfl_xor(mx, 1));
                mx = fmaxf(mx, __shfl_xor(mx, 2));
                mx = fmaxf(mx, __shfl_xor(mx, 4));
                mx = fmaxf(mx, __shfl_xor(mx, 8));
                float mn = fmaxf(m4[r], mx);
                float sc = exp2f((m4[r] - mn) * LOG2E);
                m4[r] = mn;
                float rs = 0.f;
#pragma unroll
                for (int nf = 0; nf < 4; nf++) {
                    float p = exp2f((s[nf][r] - mn) * LOG2E);
                    s[nf][r] = p;
                    rs += p;
                }
                rs += __shfl_xor(rs, 1);
                rs += __shfl_xor(rs, 2);
                rs += __shfl_xor(rs, 4);
                rs += __shfl_xor(rs, 8);
                l4[r] = l4[r] * sc + rs;
                o[0][r] *= sc; o[1][r] *= sc; o[2][r] *= sc; o[3][r] *= sc;
            }
#pragma unroll
            for (int nf = 0; nf < 4; nf++)
#pragma unroll
                for (int r = 0; r < 4; r++) {
                    int row = lg4 * 4 + r;
                    int byte = (row * 128 + (nf * 16 + lc) * 2) ^ ((row & 7) << 4);
                    *reinterpret_cast<unsigned short*>(myp + byte) = f2b(s[nf][r]);
                }
            asm volatile("s_waitcnt lgkmcnt(0)" ::: "memory");
            __builtin_amdgcn_sched_barrier(0);
#pragma unroll
            for (int k = 0; k < 2; k++) {
                int rbyte = (lc * 128 + (k * 32 + lk) * 2) ^ ((lc & 7) << 4);
                ushort8 pa = *reinterpret_cast<const ushort8*>(myp + rbyte);
#pragma unroll
                for (int df = 0; df < 4; df++) {
                    ushort8 bv2 = *reinterpret_cast<const ushort8*>(
                        VT + (df * 16 + lc) * SS + kv0 + k * 32 + lk);
                    o[df] = mfma16(pa, bv2, o[df]);
                }
            }
        }

#pragma unroll
        for (int df = 0; df < 4; df++)
#pragma unroll
            for (int r = 0; r < 4; r++)
                scomb[w][(lg4 * 4 + r) * 66 + df * 16 + lc] = o[df][r];
        if (lc == 0) {
#pragma unroll
            for (int r = 0; r < 4; r++) {
                scomb[w][(lg4 * 4 + r) * 66 + 64] = m4[r];
                scomb[w][(lg4 * 4 + r) * 66 + 65] = l4[r];
            }
        }
        __syncthreads();

        float* pp = part + bid * PSTRIDE;
        for (int idx = tid; idx < 1024; idx += 256) {
            int row = idx >> 6, col = idx & 63;
            float M = fmaxf(fmaxf(scomb[0][row * 66 + 64], scomb[1][row * 66 + 64]),
                            fmaxf(scomb[2][row * 66 + 64], scomb[3][row * 66 + 64]));
            float val = 0.f, den = 0.f;
#pragma unroll
            for (int ww = 0; ww < 4; ww++) {
                float f = exp2f((scomb[ww][row * 66 + 64] - M) * LOG2E);
                val += scomb[ww][row * 66 + col] * f;
                den += scomb[ww][row * 66 + 65] * f;
            }
            pp[row * 66 + col] = val;
            if (col == 0) {
                pp[row * 66 + 64] = M;
                pp[row * 66 + 65] = den;
            }
        }
    }
    __threadfence();
    grid.sync();

    // ---------------- phase 4: combine the 2 KV-chunk partials per group
    if (bid < 256) {
        const int g = bid;
        const int q0 = g * 16;
        const float* p0 = part + (g * 2) * PSTRIDE;
        for (int idx = tid; idx < 1024; idx += 256) {
            int row = idx >> 6, col = idx & 63;
            float M = fmaxf(p0[row * 66 + 64], p0[PSTRIDE + row * 66 + 64]);
            float val = 0.f, den = 0.f;
#pragma unroll
            for (int cc = 0; cc < 2; cc++) {
                float f = exp2f((p0[cc * PSTRIDE + row * 66 + 64] - M) * LOG2E);
                val += p0[cc * PSTRIDE + row * 66 + col] * f;
                den += p0[cc * PSTRIDE + row * 66 + 65] * f;
            }
            out[(q0 + row) * 64 + col] = val / den;
        }
    }
}

// ============================================================================
// Fallback pipeline: exact round-2 proven kernels (56 us end-to-end).
// ============================================================================
__global__ __launch_bounds__(256) void convw_kernel(
    const float* __restrict__ Wq, const float* __restrict__ Wk,
    const float* __restrict__ Wv, unsigned short* __restrict__ wb)
{
    int i = (blockIdx.x * 256 + threadIdx.x) * 4;
    const float* src;
    if (i < 65536) src = Wq + i;
    else if (i < 131072) src = Wk + (i - 65536);
    else src = Wv + (i - 131072);
    f32x4 v = *reinterpret_cast<const f32x4*>(src);
    ushort4v o;
    o[0] = f2b(v[0]); o[1] = f2b(v[1]); o[2] = f2b(v[2]); o[3] = f2b(v[3]);
    *reinterpret_cast<ushort4v*>(wb + i) = o;
}

__global__ __launch_bounds__(512) void proj_kernel(
    const float* __restrict__ x, const unsigned short* __restrict__ wb,
    const float* __restrict__ bq, const float* __restrict__ bk, const float* __restrict__ bv,
    unsigned short* __restrict__ Qs, unsigned short* __restrict__ Kb,
    unsigned short* __restrict__ VT)
{
    __shared__ float comb[8 * 3072];
    const int m0 = blockIdx.x * 16;
    const int tid = threadIdx.x;
    const int w = tid >> 6, l = tid & 63;
    const int lc = l & 15;
    const int lk = (l >> 4) * 8;

    f32x4 acc[12] = {};
    const float* xrow = x + (m0 + lc) * DM;
    const int kbase = w * 128;

    for (int kk = 0; kk < 128; kk += 32) {
        const int k0 = kbase + kk + lk;
        f32x4 u = *reinterpret_cast<const f32x4*>(xrow + k0);
        f32x4 v = *reinterpret_cast<const f32x4*>(xrow + k0 + 4);
        ushort8 a;
        a[0] = f2b(u[0]); a[1] = f2b(u[1]); a[2] = f2b(u[2]); a[3] = f2b(u[3]);
        a[4] = f2b(v[0]); a[5] = f2b(v[1]); a[6] = f2b(v[2]); a[7] = f2b(v[3]);
#pragma unroll
        for (int nf = 0; nf < 12; nf++) {
            ushort8 b = *reinterpret_cast<const ushort8*>(wb + (nf * 16 + lc) * DM + k0);
            acc[nf] = mfma16(a, b, acc[nf]);
        }
    }
#pragma unroll
    for (int nf = 0; nf < 12; nf++)
#pragma unroll
        for (int r = 0; r < 4; r++) {
            int row = (l >> 4) * 4 + r;
            comb[w * 3072 + row * 192 + nf * 16 + lc] = acc[nf][r];
        }
    __syncthreads();

    for (int idx = tid; idx < 3072; idx += 512) {
        int row = idx / 192, col = idx % 192;
        float s = 0.f;
#pragma unroll
        for (int ww = 0; ww < 8; ww++) s += comb[ww * 3072 + idx];
        int grow = m0 + row;
        if (col < 64) {
            s += bq[col];
            Qs[grow * 64 + col] = f2b(s * 0.125f);
        } else if (col < 128) {
            s += bk[col - 64];
            Kb[grow * 64 + col - 64] = f2b(s);
        } else {
            s += bv[col - 128];
            VT[(col - 128) * SS + grow] = f2b(s);
        }
    }
}

__global__ __launch_bounds__(256) void attn_part_kernel(
    const unsigned short* __restrict__ Qs, const unsigned short* __restrict__ Kb,
    const unsigned short* __restrict__ VT, float* __restrict__ part)
{
    __shared__ unsigned short plds[4][16 * 64];
    __shared__ float comb[4][16 * 66];

    const int bid = blockIdx.x;
    const int g = bid >> 2, c = bid & 3;
    const int q0 = g * 16;
    const int tid = threadIdx.x;
    const int w = tid >> 6, l = tid & 63;
    const int lc = l & 15;
    const int lg4 = l >> 4;
    const int lk = lg4 * 8;

    const int T = g / 4 + 1;
    const int W0 = c * 4 + w;

    ushort8 aq0 = *reinterpret_cast<const ushort8*>(Qs + (q0 + lc) * 64 + lk);
    ushort8 aq1 = *reinterpret_cast<const ushort8*>(Qs + (q0 + lc) * 64 + 32 + lk);

    float m4[4], l4[4];
    f32x4 o[4] = {};
#pragma unroll
    for (int r = 0; r < 4; r++) { m4[r] = NEGHUGE; l4[r] = 0.f; }

    char* myp = reinterpret_cast<char*>(plds[w]);

    for (int t = W0; t < T; t += 16) {
        const int kv0 = t * 64;
        f32x4 s[4] = {};
#pragma unroll
        for (int nf = 0; nf < 4; nf++) {
            const unsigned short* kr = Kb + (kv0 + nf * 16 + lc) * 64;
            ushort8 b0 = *reinterpret_cast<const ushort8*>(kr + lk);
            ushort8 b1 = *reinterpret_cast<const ushort8*>(kr + 32 + lk);
            s[nf] = mfma16(aq0, b0, s[nf]);
            s[nf] = mfma16(aq1, b1, s[nf]);
        }
        if (kv0 + 63 > q0) {
#pragma unroll
            for (int nf = 0; nf < 4; nf++)
#pragma unroll
                for (int r = 0; r < 4; r++) {
                    int colg = kv0 + nf * 16 + lc;
                    int rowg = q0 + lg4 * 4 + r;
                    if (colg > rowg) s[nf][r] = NEGHUGE;
                }
        }
#pragma unroll
        for (int r = 0; r < 4; r++) {
            float mx = fmaxf(fmaxf(s[0][r], s[1][r]), fmaxf(s[2][r], s[3][r]));
            mx = fmaxf(mx, __shfl_xor(mx, 1));
            mx = fmaxf(mx, __shfl_xor(mx, 2));
            mx = fmaxf(mx, __shfl_xor(mx, 4));
            mx = fmaxf(mx, __shfl_xor(mx, 8));
            float mn = fmaxf(m4[r], mx);
            float sc = exp2f((m4[r] - mn) * LOG2E);
            m4[r] = mn;
            float rs = 0.f;
#pragma unroll
            for (int nf = 0; nf < 4; nf++) {
                float p = exp2f((s[nf][r] - mn) * LOG2E);
                s[nf][r] = p;
                rs += p;
            }
            rs += __shfl_xor(rs, 1);
            rs += __shfl_xor(rs, 2);
            rs += __shfl_xor(rs, 4);
            rs += __shfl_xor(rs, 8);
            l4[r] = l4[r] * sc + rs;
            o[0][r] *= sc; o[1][r] *= sc; o[2][r] *= sc; o[3][r] *= sc;
        }
#pragma unroll
        for (int nf = 0; nf < 4; nf++)
#pragma unroll
            for (int r = 0; r < 4; r++) {
                int row = lg4 * 4 + r;
                int byte = (row * 128 + (nf * 16 + lc) * 2) ^ ((row & 7) << 4);
                *reinterpret_cast<unsigned short*>(myp + byte) = f2b(s[nf][r]);
            }
        asm volatile("s_waitcnt lgkmcnt(0)" ::: "memory");
        __builtin_amdgcn_sched_barrier(0);
#pragma unroll
        for (int k = 0; k < 2; k++) {
            int rbyte = (lc * 128 + (k * 32 + lk) * 2) ^ ((lc & 7) << 4);
            ushort8 pa = *reinterpret_cast<const ushort8*>(myp + rbyte);
#pragma unroll
            for (int df = 0; df < 4; df++) {
                ushort8 bv2 = *reinterpret_cast<const ushort8*>(
                    VT + (df * 16 + lc) * SS + kv0 + k * 32 + lk);
                o[df] = mfma16(pa, bv2, o[df]);
            }
        }
    }

#pragma unroll
    for (int df = 0; df < 4; df++)
#pragma unroll
        for (int r = 0; r < 4; r++)
            comb[w][(lg4 * 4 + r) * 66 + df * 16 + lc] = o[df][r];
    if (lc == 0) {
#pragma unroll
        for (int r = 0; r < 4; r++) {
            comb[w][(lg4 * 4 + r) * 66 + 64] = m4[r];
            comb[w][(lg4 * 4 + r) * 66 + 65] = l4[r];
        }
    }
    __syncthreads();

    float* pp = part + bid * PSTRIDE;
    for (int idx = tid; idx < 1024; idx += 256) {
        int row = idx >> 6, col = idx & 63;
        float M = fmaxf(fmaxf(comb[0][row * 66 + 64], comb[1][row * 66 + 64]),
                        fmaxf(comb[2][row * 66 + 64], comb[3][row * 66 + 64]));
        float val = 0.f, den = 0.f;
#pragma unroll
        for (int ww = 0; ww < 4; ww++) {
            float f = exp2f((comb[ww][row * 66 + 64] - M) * LOG2E);
            val += comb[ww][row * 66 + col] * f;
            den += comb[ww][row * 66 + 65] * f;
        }
        pp[row * 66 + col] = val;
        if (col == 0) {
            pp[row * 66 + 64] = M;
            pp[row * 66 + 65] = den;
        }
    }
}

__global__ __launch_bounds__(256) void attn_comb_kernel(
    const float* __restrict__ part, float* __restrict__ out)
{
    const int g = blockIdx.x;
    const int q0 = g * 16;
    const float* p0 = part + (g * 4) * PSTRIDE;
    for (int idx = threadIdx.x; idx < 1024; idx += 256) {
        int row = idx >> 6, col = idx & 63;
        float M = NEGHUGE;
#pragma unroll
        for (int cc = 0; cc < 4; cc++)
            M = fmaxf(M, p0[cc * PSTRIDE + row * 66 + 64]);
        float val = 0.f, den = 0.f;
#pragma unroll
        for (int cc = 0; cc < 4; cc++) {
            float f = exp2f((p0[cc * PSTRIDE + row * 66 + 64] - M) * LOG2E);
            val += p0[cc * PSTRIDE + row * 66 + col] * f;
            den += p0[cc * PSTRIDE + row * 66 + 65] * f;
        }
        out[(q0 + row) * 64 + col] = val / den;
    }
}

extern "C" void kernel_launch(void* const* d_in, const int* in_sizes, int n_in,
                              void* d_out, int out_size, void* d_ws, size_t ws_size,
                              hipStream_t stream) {
    const float* x  = (const float*)d_in[0];
    const float* Wq = (const float*)d_in[1];
    const float* bq = (const float*)d_in[2];
    const float* Wk = (const float*)d_in[3];
    const float* bk = (const float*)d_in[4];
    const float* Wv = (const float*)d_in[5];
    const float* bv = (const float*)d_in[6];
    float* out = (float*)d_out;

    char* ws = (char*)d_ws;
    unsigned short* wb = (unsigned short*)ws;               // 393216 B
    unsigned short* Qs = (unsigned short*)(ws + 393216);    // 524288 B
    unsigned short* Kb = (unsigned short*)(ws + 917504);    // 524288 B
    unsigned short* VT = (unsigned short*)(ws + 1441792);   // 524288 B
    float* part = (float*)(ws + 1966080);                   // up to 4325376 B

    void* args[] = {(void*)&x, (void*)&Wq, (void*)&bq, (void*)&Wk, (void*)&bk,
                    (void*)&Wv, (void*)&bv, (void*)&out, (void*)&wb, (void*)&Qs,
                    (void*)&Kb, (void*)&VT, (void*)&part};
    hipError_t err = hipLaunchCooperativeKernel((const void*)fused_kernel,
                                                dim3(512), dim3(256), args, 0, stream);
    if (err != hipSuccess) {
        (void)hipGetLastError();  // clear sticky error, fall back to proven pipeline
        convw_kernel<<<dim3(192), dim3(256), 0, stream>>>(Wq, Wk, Wv, wb);
        proj_kernel<<<dim3(256), dim3(512), 0, stream>>>(x, wb, bq, bk, bv, Qs, Kb, VT);
        attn_part_kernel<<<dim3(1024), dim3(256), 0, stream>>>(Qs, Kb, VT, part);
        attn_comb_kernel<<<dim3(256), dim3(256), 0, stream>>>(part, out);
    }
}

// Round 6
// 60.796 us; speedup vs baseline: 5.6957x; 5.6957x over previous
//
#include <hip/hip_runtime.h>

#define SS 4096
#define DM 1024

typedef __attribute__((ext_vector_type(4))) float f32x4;
typedef __attribute__((ext_vector_type(8))) __bf16 bf16x8;
typedef __attribute__((ext_vector_type(8))) unsigned short ushort8;
typedef __attribute__((ext_vector_type(4))) unsigned short ushort4v;

#define NEGHUGE -3.0e38f
#define LOG2E 1.44269504f

__device__ __forceinline__ unsigned short f2b(float f) {
    unsigned u = __builtin_bit_cast(unsigned, f);
    u += 0x7fffu + ((u >> 16) & 1u);
    return (unsigned short)(u >> 16);
}

__device__ __forceinline__ f32x4 mfma16(ushort8 a, ushort8 b, f32x4 c) {
    return __builtin_amdgcn_mfma_f32_16x16x32_bf16(
        __builtin_bit_cast(bf16x8, a), __builtin_bit_cast(bf16x8, b), c, 0, 0, 0);
}

// ---------------- kernel 1: convert W (3x [64][1024] f32) -> wb bf16 [192][1024]
__global__ __launch_bounds__(256) void convw_kernel(
    const float* __restrict__ Wq, const float* __restrict__ Wk,
    const float* __restrict__ Wv, unsigned short* __restrict__ wb)
{
    int i = (blockIdx.x * 256 + threadIdx.x) * 4;  // 192*1024 = 196608 elems
    const float* src;
    if (i < 65536) src = Wq + i;
    else if (i < 131072) src = Wk + (i - 65536);
    else src = Wv + (i - 131072);
    f32x4 v = *reinterpret_cast<const f32x4*>(src);
    ushort4v o;
    o[0] = f2b(v[0]); o[1] = f2b(v[1]); o[2] = f2b(v[2]); o[3] = f2b(v[3]);
    *reinterpret_cast<ushort4v*>(wb + i) = o;
}

// ---------------- kernel 2: QKV projection (R3-proven).
// grid 256 (16 rows each), 4 waves split K=1024 into 4x256. MFMA 16x16x32 bf16.
// Writes Qs = (xWq+bq)/8 (bf16), Kb (bf16), VT = V transposed [64][4096] (bf16).
__global__ __launch_bounds__(256) void proj_kernel(
    const float* __restrict__ x, const unsigned short* __restrict__ wb,
    const float* __restrict__ bq, const float* __restrict__ bk, const float* __restrict__ bv,
    unsigned short* __restrict__ Qs, unsigned short* __restrict__ Kb,
    unsigned short* __restrict__ VT)
{
    __shared__ float comb[4 * 16 * 196];  // 50KB, row stride 196 (pad vs 192)
    const int m0 = blockIdx.x * 16;
    const int tid = threadIdx.x;
    const int w = tid >> 6, l = tid & 63;
    const int lc = l & 15;          // frag row/col index
    const int lk = (l >> 4) * 8;    // k sub-offset

    f32x4 acc[12] = {};
    const float* xrow = x + (m0 + lc) * DM;
    const int kbase = w * 256;

    for (int kk = 0; kk < 256; kk += 32) {
        const int k0 = kbase + kk + lk;
        f32x4 u = *reinterpret_cast<const f32x4*>(xrow + k0);
        f32x4 v = *reinterpret_cast<const f32x4*>(xrow + k0 + 4);
        ushort8 a;
        a[0] = f2b(u[0]); a[1] = f2b(u[1]); a[2] = f2b(u[2]); a[3] = f2b(u[3]);
        a[4] = f2b(v[0]); a[5] = f2b(v[1]); a[6] = f2b(v[2]); a[7] = f2b(v[3]);
#pragma unroll
        for (int nf = 0; nf < 12; nf++) {
            ushort8 b = *reinterpret_cast<const ushort8*>(wb + (nf * 16 + lc) * DM + k0);
            acc[nf] = mfma16(a, b, acc[nf]);
        }
    }

    // write partials: C/D layout row=(l>>4)*4+r, col = nf*16 + lc
#pragma unroll
    for (int nf = 0; nf < 12; nf++)
#pragma unroll
        for (int r = 0; r < 4; r++) {
            int row = (l >> 4) * 4 + r;
            comb[w * 3136 + row * 196 + nf * 16 + lc] = acc[nf][r];
        }
    __syncthreads();

    for (int idx = tid; idx < 3072; idx += 256) {
        int row = idx / 192, col = idx % 192;
        int off = row * 196 + col;
        float s = comb[off] + comb[3136 + off] + comb[6272 + off] + comb[9408 + off];
        int grow = m0 + row;
        if (col < 64) {
            s += bq[col];
            Qs[grow * 64 + col] = f2b(s * 0.125f);  // fold 1/sqrt(d_k)=1/8 into Q (exact)
        } else if (col < 128) {
            s += bk[col - 64];
            Kb[grow * 64 + col - 64] = f2b(s);
        } else {
            s += bv[col - 128];
            VT[(col - 128) * SS + grow] = f2b(s);
        }
    }
}

// ---------------- kernel 3: causal flash attention, single pass.
// grid 256 x 1024 threads (16 waves). Block g = Q rows [16g, 16g+16).
// Causal tile list [0,T) split across the 16 waves, stride 16 (same 16-way
// split as R2's 4-block scheme, but the combine is block-internal: no part
// buffer, no second kernel). LDS: 32KB P + 67.6KB comb = 100KB, 1 block/CU.
__global__ __launch_bounds__(1024) void attn_kernel(
    const unsigned short* __restrict__ Qs, const unsigned short* __restrict__ Kb,
    const unsigned short* __restrict__ VT, float* __restrict__ out)
{
    __shared__ unsigned short plds[16][16 * 64];  // per-wave P tiles (XOR-swizzled)
    __shared__ float scomb[16][16 * 66];          // per-wave partials (+m,+l)

    const int g = blockIdx.x;
    const int q0 = g * 16;
    const int tid = threadIdx.x;
    const int w = tid >> 6, l = tid & 63;
    const int lc = l & 15;
    const int lg4 = l >> 4;
    const int lk = lg4 * 8;

    const int T = g / 4 + 1;        // causal 64-wide tiles for this group

    // Q fragments (Q already scaled by 1/8)
    ushort8 aq0 = *reinterpret_cast<const ushort8*>(Qs + (q0 + lc) * 64 + lk);
    ushort8 aq1 = *reinterpret_cast<const ushort8*>(Qs + (q0 + lc) * 64 + 32 + lk);

    float m4[4], l4[4];
    f32x4 o[4] = {};
#pragma unroll
    for (int r = 0; r < 4; r++) { m4[r] = NEGHUGE; l4[r] = 0.f; }

    char* myp = reinterpret_cast<char*>(plds[w]);

    for (int t = w; t < T; t += 16) {
        const int kv0 = t * 64;
        f32x4 s[4] = {};
#pragma unroll
        for (int nf = 0; nf < 4; nf++) {
            const unsigned short* kr = Kb + (kv0 + nf * 16 + lc) * 64;
            ushort8 b0 = *reinterpret_cast<const ushort8*>(kr + lk);
            ushort8 b1 = *reinterpret_cast<const ushort8*>(kr + 32 + lk);
            s[nf] = mfma16(aq0, b0, s[nf]);
            s[nf] = mfma16(aq1, b1, s[nf]);
        }
        // causal mask (only the diagonal-overlapping tile needs it)
        if (kv0 + 63 > q0) {
#pragma unroll
            for (int nf = 0; nf < 4; nf++)
#pragma unroll
                for (int r = 0; r < 4; r++) {
                    int colg = kv0 + nf * 16 + lc;
                    int rowg = q0 + lg4 * 4 + r;
                    if (colg > rowg) s[nf][r] = NEGHUGE;
                }
        }
        // online softmax (branchless; NEGHUGE pollution annihilated by weights)
#pragma unroll
        for (int r = 0; r < 4; r++) {
            float mx = fmaxf(fmaxf(s[0][r], s[1][r]), fmaxf(s[2][r], s[3][r]));
            mx = fmaxf(mx, __shfl_xor(mx, 1));
            mx = fmaxf(mx, __shfl_xor(mx, 2));
            mx = fmaxf(mx, __shfl_xor(mx, 4));
            mx = fmaxf(mx, __shfl_xor(mx, 8));
            float mn = fmaxf(m4[r], mx);
            float sc = exp2f((m4[r] - mn) * LOG2E);
            m4[r] = mn;
            float rs = 0.f;
#pragma unroll
            for (int nf = 0; nf < 4; nf++) {
                float p = exp2f((s[nf][r] - mn) * LOG2E);
                s[nf][r] = p;
                rs += p;
            }
            rs += __shfl_xor(rs, 1);
            rs += __shfl_xor(rs, 2);
            rs += __shfl_xor(rs, 4);
            rs += __shfl_xor(rs, 8);
            l4[r] = l4[r] * sc + rs;
            o[0][r] *= sc; o[1][r] *= sc; o[2][r] *= sc; o[3][r] *= sc;
        }
        // P -> LDS (bf16, XOR swizzle byte ^= (row&7)<<4)
#pragma unroll
        for (int nf = 0; nf < 4; nf++)
#pragma unroll
            for (int r = 0; r < 4; r++) {
                int row = lg4 * 4 + r;
                int byte = (row * 128 + (nf * 16 + lc) * 2) ^ ((row & 7) << 4);
                *reinterpret_cast<unsigned short*>(myp + byte) = f2b(s[nf][r]);
            }
        asm volatile("s_waitcnt lgkmcnt(0)" ::: "memory");
        __builtin_amdgcn_sched_barrier(0);
        // PV: A = P from LDS (swizzled b128), B = VT rows (contiguous 16B)
#pragma unroll
        for (int k = 0; k < 2; k++) {
            int rbyte = (lc * 128 + (k * 32 + lk) * 2) ^ ((lc & 7) << 4);
            ushort8 pa = *reinterpret_cast<const ushort8*>(myp + rbyte);
#pragma unroll
            for (int df = 0; df < 4; df++) {
                ushort8 bv2 = *reinterpret_cast<const ushort8*>(
                    VT + (df * 16 + lc) * SS + kv0 + k * 32 + lk);
                o[df] = mfma16(pa, bv2, o[df]);
            }
        }
    }

    // write per-wave partials
#pragma unroll
    for (int df = 0; df < 4; df++)
#pragma unroll
        for (int r = 0; r < 4; r++)
            scomb[w][(lg4 * 4 + r) * 66 + df * 16 + lc] = o[df][r];
    if (lc == 0) {
#pragma unroll
        for (int r = 0; r < 4; r++) {
            scomb[w][(lg4 * 4 + r) * 66 + 64] = m4[r];
            scomb[w][(lg4 * 4 + r) * 66 + 65] = l4[r];
        }
    }
    __syncthreads();

    // combine 16 wave-partials, normalize, write f32 out.
    // 1024 threads = exactly 16 rows x 64 cols.
    {
        int row = tid >> 6, col = tid & 63;
        float M = NEGHUGE;
#pragma unroll
        for (int ww = 0; ww < 16; ww++)
            M = fmaxf(M, scomb[ww][row * 66 + 64]);
        float val = 0.f, den = 0.f;
#pragma unroll
        for (int ww = 0; ww < 16; ww++) {
            float f = exp2f((scomb[ww][row * 66 + 64] - M) * LOG2E);
            val += scomb[ww][row * 66 + col] * f;
            den += scomb[ww][row * 66 + 65] * f;
        }
        out[(q0 + row) * 64 + col] = val / den;
    }
}

extern "C" void kernel_launch(void* const* d_in, const int* in_sizes, int n_in,
                              void* d_out, int out_size, void* d_ws, size_t ws_size,
                              hipStream_t stream) {
    const float* x  = (const float*)d_in[0];
    const float* Wq = (const float*)d_in[1];
    const float* bq = (const float*)d_in[2];
    const float* Wk = (const float*)d_in[3];
    const float* bk = (const float*)d_in[4];
    const float* Wv = (const float*)d_in[5];
    const float* bv = (const float*)d_in[6];
    float* out = (float*)d_out;

    char* ws = (char*)d_ws;
    unsigned short* wb = (unsigned short*)ws;               // 393216 B
    unsigned short* Qs = (unsigned short*)(ws + 393216);    // 524288 B
    unsigned short* Kb = (unsigned short*)(ws + 917504);    // 524288 B
    unsigned short* VT = (unsigned short*)(ws + 1441792);   // 524288 B

    convw_kernel<<<dim3(192), dim3(256), 0, stream>>>(Wq, Wk, Wv, wb);
    proj_kernel<<<dim3(256), dim3(256), 0, stream>>>(x, wb, bq, bk, bv, Qs, Kb, VT);
    attn_kernel<<<dim3(256), dim3(1024), 0, stream>>>(Qs, Kb, VT, out);
}

// Round 8
// 59.610 us; speedup vs baseline: 5.8091x; 1.0199x over previous
//
#include <hip/hip_runtime.h>

#define SS 4096
#define DM 1024
#define PSTRIDE 1056  // 16*66 f32 per block partial

typedef __attribute__((ext_vector_type(4))) float f32x4;
typedef __attribute__((ext_vector_type(8))) __bf16 bf16x8;
typedef __attribute__((ext_vector_type(8))) unsigned short ushort8;
typedef __attribute__((ext_vector_type(4))) unsigned short ushort4v;
typedef __attribute__((ext_vector_type(2))) unsigned int uint2v;

#define NEGHUGE -3.0e38f
#define LOG2E 1.44269504f

__device__ __forceinline__ unsigned short f2b(float f) {
    unsigned u = __builtin_bit_cast(unsigned, f);
    u += 0x7fffu + ((u >> 16) & 1u);
    return (unsigned short)(u >> 16);
}

__device__ __forceinline__ f32x4 mfma16(ushort8 a, ushort8 b, f32x4 c) {
    return __builtin_amdgcn_mfma_f32_16x16x32_bf16(
        __builtin_bit_cast(bf16x8, a), __builtin_bit_cast(bf16x8, b), c, 0, 0, 0);
}

// ---------------- kernel 1: convert W (3x [64][1024] f32) -> wb bf16 [192][1024]
__global__ __launch_bounds__(256) void convw_kernel(
    const float* __restrict__ Wq, const float* __restrict__ Wk,
    const float* __restrict__ Wv, unsigned short* __restrict__ wb)
{
    int i = (blockIdx.x * 256 + threadIdx.x) * 4;
    const float* src;
    if (i < 65536) src = Wq + i;
    else if (i < 131072) src = Wk + (i - 65536);
    else src = Wv + (i - 131072);
    f32x4 v = *reinterpret_cast<const f32x4*>(src);
    ushort4v o;
    o[0] = f2b(v[0]); o[1] = f2b(v[1]); o[2] = f2b(v[2]); o[3] = f2b(v[3]);
    *reinterpret_cast<ushort4v*>(wb + i) = o;
}

// ---------------- kernel 2: QKV projection, high-TLP version.
// grid 1024: block (mt = bid>>2, fg = bid&3). 16 rows x 48 cols per block;
// 4 waves split K=1024 into 4x256; small LDS combine. 4 blocks/CU.
__global__ __launch_bounds__(256) void proj_kernel(
    const float* __restrict__ x, const unsigned short* __restrict__ wb,
    const float* __restrict__ bq, const float* __restrict__ bk, const float* __restrict__ bv,
    unsigned short* __restrict__ Qs, unsigned short* __restrict__ Kb,
    unsigned short* __restrict__ VT)
{
    __shared__ float comb[4 * 16 * 52];  // 13.3KB
    const int bid = blockIdx.x;
    const int m0 = (bid >> 2) * 16;
    const int fg = bid & 3;
    const int tid = threadIdx.x;
    const int w = tid >> 6, l = tid & 63;
    const int lc = l & 15;
    const int lg4 = l >> 4;
    const int lk = lg4 * 8;

    f32x4 acc[3] = {};
    const float* xrow = x + (m0 + lc) * DM;
    const unsigned short* wbase = wb + (fg * 48 + lc) * DM;
    const int kbase = w * 256;

    for (int kk = 0; kk < 256; kk += 32) {
        const int k0 = kbase + kk + lk;
        f32x4 u = *reinterpret_cast<const f32x4*>(xrow + k0);
        f32x4 v = *reinterpret_cast<const f32x4*>(xrow + k0 + 4);
        ushort8 a;
        a[0] = f2b(u[0]); a[1] = f2b(u[1]); a[2] = f2b(u[2]); a[3] = f2b(u[3]);
        a[4] = f2b(v[0]); a[5] = f2b(v[1]); a[6] = f2b(v[2]); a[7] = f2b(v[3]);
#pragma unroll
        for (int nf = 0; nf < 3; nf++) {
            ushort8 b = *reinterpret_cast<const ushort8*>(wbase + nf * 16 * DM + k0);
            acc[nf] = mfma16(a, b, acc[nf]);
        }
    }

#pragma unroll
    for (int nf = 0; nf < 3; nf++)
#pragma unroll
        for (int r = 0; r < 4; r++)
            comb[w * 832 + (lg4 * 4 + r) * 52 + nf * 16 + lc] = acc[nf][r];
    __syncthreads();

    for (int idx = tid; idx < 768; idx += 256) {
        int row = idx / 48, col = idx % 48;
        int off = row * 52 + col;
        float s = comb[off] + comb[832 + off] + comb[1664 + off] + comb[2496 + off];
        int grow = m0 + row;
        int gcol = fg * 48 + col;
        if (gcol < 64) {
            s += bq[gcol];
            Qs[grow * 64 + gcol] = f2b(s * 0.125f);  // fold 1/sqrt(64) into Q
        } else if (gcol < 128) {
            s += bk[gcol - 64];
            Kb[grow * 64 + gcol - 64] = f2b(s);
        } else {
            s += bv[gcol - 128];
            VT[(gcol - 128) * SS + grow] = f2b(s);
        }
    }
}

// ---------------- kernel 3: attention split-KV partials, SWAPPED-QK^T layout.
// grid 1024: bid -> (g = 255 - bid>>2, c = bid&3). Group g = Q rows [16g,16g+16).
// Tile list [0,T) split 16 ways (4 chunks x 4 waves), stride 16.
// Swapped layout: lane (lg4,lc) holds scores S[kv=kv0+nf*16+lg4*4+r][q=q0+lc]
// -> softmax per q-row is in-lane (16 regs) + 2 shfl_xor (16,32).
// P->PV relayout via packed bf16 + tiny wave-local LDS bounce (144B/line):
// dword slot s of line lc holds kv {2s,2s+1}; PV B-frag for chunk cc reads
// slots 16cc+4*lg4 .. +3  (= kv cc*32+lg4*8+{0..7}, matching k=lg4*8+j).
__global__ __launch_bounds__(256) void attn_part_kernel(
    const unsigned short* __restrict__ Qs, const unsigned short* __restrict__ Kb,
    const unsigned short* __restrict__ VT, float* __restrict__ part)
{
    __shared__ __align__(16) char plds[4 * 2304];  // 9.2KB: per-wave P bounce
    __shared__ float scomb[4][16 * 66];            // 16.9KB

    const int bid = blockIdx.x;
    const int g = 255 - (bid >> 2);   // big groups dispatch first
    const int c = bid & 3;
    const int q0 = g * 16;
    const int tid = threadIdx.x;
    const int w = tid >> 6, l = tid & 63;
    const int lc = l & 15;
    const int lg4 = l >> 4;
    const int lk = lg4 * 8;

    const int T = g / 4 + 1;
    const int W0 = c * 4 + w;

    // Q fragments (B-operand now): lane holds Q[q0+lc][lk..lk+8) (pre-scaled /8)
    ushort8 aq0 = *reinterpret_cast<const ushort8*>(Qs + (q0 + lc) * 64 + lk);
    ushort8 aq1 = *reinterpret_cast<const ushort8*>(Qs + (q0 + lc) * 64 + 32 + lk);

    float m4 = NEGHUGE, l4 = 0.f;   // per-lane: q-row = q0+lc
    f32x4 o[4] = {};                 // o[df][r] = O[d=df*16+lg4*4+r][q=q0+lc]

    char* myp = plds + w * 2304;

    for (int t = W0; t < T; t += 16) {
        const int kv0 = t * 64;
        // QK^T swapped: s[nf] = K-frag x Q-frag
        f32x4 s[4] = {};
#pragma unroll
        for (int nf = 0; nf < 4; nf++) {
            const unsigned short* kr = Kb + (kv0 + nf * 16 + lc) * 64;
            ushort8 b0 = *reinterpret_cast<const ushort8*>(kr + lk);
            ushort8 b1 = *reinterpret_cast<const ushort8*>(kr + 32 + lk);
            s[nf] = mfma16(b0, aq0, s[nf]);   // A=K, B=Q
            s[nf] = mfma16(b1, aq1, s[nf]);
        }
        // preload V fragments (consumed after softmax; hidden under VALU)
        ushort8 av[2][4];
#pragma unroll
        for (int cc = 0; cc < 2; cc++)
#pragma unroll
            for (int df = 0; df < 4; df++)
                av[cc][df] = *reinterpret_cast<const ushort8*>(
                    VT + (df * 16 + lc) * SS + kv0 + cc * 32 + lk);

        // causal mask: mask iff tile overlaps/crosses the diagonal for ANY row
        // (kv_max = kv0+63 exceeds q_min = q0)  [R7 bug: had q0+15 here]
        if (kv0 + 63 > q0) {
#pragma unroll
            for (int nf = 0; nf < 4; nf++)
#pragma unroll
                for (int r = 0; r < 4; r++) {
                    int kvi = kv0 + nf * 16 + lg4 * 4 + r;
                    if (kvi > q0 + lc) s[nf][r] = NEGHUGE;
                }
        }
        // softmax for q-row (q0+lc): in-lane tree + 2 shfls
        float mx01 = fmaxf(fmaxf(s[0][0], s[0][1]), fmaxf(s[0][2], s[0][3]));
        float mx11 = fmaxf(fmaxf(s[1][0], s[1][1]), fmaxf(s[1][2], s[1][3]));
        float mx21 = fmaxf(fmaxf(s[2][0], s[2][1]), fmaxf(s[2][2], s[2][3]));
        float mx31 = fmaxf(fmaxf(s[3][0], s[3][1]), fmaxf(s[3][2], s[3][3]));
        float mx = fmaxf(fmaxf(mx01, mx11), fmaxf(mx21, mx31));
        mx = fmaxf(mx, __shfl_xor(mx, 16));
        mx = fmaxf(mx, __shfl_xor(mx, 32));
        float mn = fmaxf(m4, mx);
        float sc = exp2f((m4 - mn) * LOG2E);
        m4 = mn;
        float rs = 0.f;
#pragma unroll
        for (int nf = 0; nf < 4; nf++)
#pragma unroll
            for (int r = 0; r < 4; r++) {
                float p = exp2f((s[nf][r] - mn) * LOG2E);
                s[nf][r] = p;
                rs += p;
            }
        rs += __shfl_xor(rs, 16);
        rs += __shfl_xor(rs, 32);
        l4 = l4 * sc + rs;
#pragma unroll
        for (int df = 0; df < 4; df++) {
            o[df][0] *= sc; o[df][1] *= sc; o[df][2] *= sc; o[df][3] *= sc;
        }
        // pack P to bf16 pairs and bounce through wave-local LDS.
#pragma unroll
        for (int nf = 0; nf < 4; nf++) {
            unsigned p01 = (unsigned)f2b(s[nf][0]) | ((unsigned)f2b(s[nf][1]) << 16);
            unsigned p23 = (unsigned)f2b(s[nf][2]) | ((unsigned)f2b(s[nf][3]) << 16);
            uint2v pk; pk[0] = p01; pk[1] = p23;
            *reinterpret_cast<uint2v*>(myp + lc * 144 + (nf * 8 + lg4 * 2) * 4) = pk;
        }
        asm volatile("s_waitcnt lgkmcnt(0)" ::: "memory");
        __builtin_amdgcn_sched_barrier(0);
        // read B-frag for PV: chunk cc needs slots 16cc+4*lg4 .. +3 at line lc
#pragma unroll
        for (int cc = 0; cc < 2; cc++) {
            int S = 16 * cc + 4 * lg4;
            ushort8 pb = *reinterpret_cast<const ushort8*>(myp + lc * 144 + S * 4);
#pragma unroll
            for (int df = 0; df < 4; df++)
                o[df] = mfma16(av[cc][df], pb, o[df]);   // A=V^T, B=P
        }
    }

    // per-wave partials: lane (lg4,lc) -> q-row lc, d = df*16+lg4*4+r
#pragma unroll
    for (int df = 0; df < 4; df++)
#pragma unroll
        for (int r = 0; r < 4; r++)
            scomb[w][lc * 66 + df * 16 + lg4 * 4 + r] = o[df][r];
    if (lg4 == 0) {
        scomb[w][lc * 66 + 64] = m4;
        scomb[w][lc * 66 + 65] = l4;
    }
    __syncthreads();

    // combine 4 wave-partials -> one unnormalized block partial
    float* pp = part + bid * PSTRIDE;
    for (int idx = tid; idx < 1024; idx += 256) {
        int row = idx >> 6, col = idx & 63;
        float M = fmaxf(fmaxf(scomb[0][row * 66 + 64], scomb[1][row * 66 + 64]),
                        fmaxf(scomb[2][row * 66 + 64], scomb[3][row * 66 + 64]));
        float val = 0.f, den = 0.f;
#pragma unroll
        for (int ww = 0; ww < 4; ww++) {
            float f = exp2f((scomb[ww][row * 66 + 64] - M) * LOG2E);
            val += scomb[ww][row * 66 + col] * f;
            den += scomb[ww][row * 66 + 65] * f;
        }
        pp[row * 66 + col] = val;
        if (col == 0) {
            pp[row * 66 + 64] = M;
            pp[row * 66 + 65] = den;
        }
    }
}

// ---------------- kernel 4: combine the 4 KV-chunk partials per group.
__global__ __launch_bounds__(256) void attn_comb_kernel(
    const float* __restrict__ part, float* __restrict__ out)
{
    const int b = blockIdx.x;
    const int g = 255 - b;            // matches attn_part mapping
    const int q0 = g * 16;
    const float* p0 = part + (b * 4) * PSTRIDE;
    for (int idx = threadIdx.x; idx < 1024; idx += 256) {
        int row = idx >> 6, col = idx & 63;
        float M = NEGHUGE;
#pragma unroll
        for (int cc = 0; cc < 4; cc++)
            M = fmaxf(M, p0[cc * PSTRIDE + row * 66 + 64]);
        float val = 0.f, den = 0.f;
#pragma unroll
        for (int cc = 0; cc < 4; cc++) {
            float f = exp2f((p0[cc * PSTRIDE + row * 66 + 64] - M) * LOG2E);
            val += p0[cc * PSTRIDE + row * 66 + col] * f;
            den += p0[cc * PSTRIDE + row * 66 + 65] * f;
        }
        out[(q0 + row) * 64 + col] = val / den;
    }
}

extern "C" void kernel_launch(void* const* d_in, const int* in_sizes, int n_in,
                              void* d_out, int out_size, void* d_ws, size_t ws_size,
                              hipStream_t stream) {
    const float* x  = (const float*)d_in[0];
    const float* Wq = (const float*)d_in[1];
    const float* bq = (const float*)d_in[2];
    const float* Wk = (const float*)d_in[3];
    const float* bk = (const float*)d_in[4];
    const float* Wv = (const float*)d_in[5];
    const float* bv = (const float*)d_in[6];
    float* out = (float*)d_out;

    char* ws = (char*)d_ws;
    unsigned short* wb = (unsigned short*)ws;               // 393216 B
    unsigned short* Qs = (unsigned short*)(ws + 393216);    // 524288 B
    unsigned short* Kb = (unsigned short*)(ws + 917504);    // 524288 B
    unsigned short* VT = (unsigned short*)(ws + 1441792);   // 524288 B
    float* part = (float*)(ws + 1966080);                   // 1024*1056*4 B

    convw_kernel<<<dim3(192), dim3(256), 0, stream>>>(Wq, Wk, Wv, wb);
    proj_kernel<<<dim3(1024), dim3(256), 0, stream>>>(x, wb, bq, bk, bv, Qs, Kb, VT);
    attn_part_kernel<<<dim3(1024), dim3(256), 0, stream>>>(Qs, Kb, VT, part);
    attn_comb_kernel<<<dim3(256), dim3(256), 0, stream>>>(part, out);
}